// Round 4
// baseline (214.757 us; speedup 1.0000x reference)
//
#include <hip/hip_runtime.h>
#include <hip/hip_bf16.h>
#include <cstdint>
#include <math.h>

#define BATCH 4
#define SDIM  2048
#define DDIM  1024
#define QKVN  3072   // fused Q|K|V output width

typedef __attribute__((ext_vector_type(8))) short bf16x8;
typedef __attribute__((ext_vector_type(8))) unsigned short u16x8;
typedef __attribute__((ext_vector_type(4))) float f32x4;

__device__ __forceinline__ float bf2f(unsigned short u) {
  union { unsigned int i; float f; } v; v.i = ((unsigned int)u) << 16; return v.f;
}
__device__ __forceinline__ unsigned short f2bf(float f) {
  unsigned int i = __float_as_uint(f);
  return (unsigned short)((i + 0x7FFFu + ((i >> 16) & 1u)) >> 16);  // RNE
}

#define GLOAD16(gp, lp) \
  __builtin_amdgcn_global_load_lds((const __attribute__((address_space(1))) void*)(gp), \
                                   (__attribute__((address_space(3))) void*)(lp), 16, 0, 0)

// ---------------- fp32 -> bf16 convert (single src) ----------------
__global__ void cvt_f32_bf16(const float* __restrict__ in,
                             unsigned short* __restrict__ out, int n) {
  int i0 = (blockIdx.x * 256 + threadIdx.x) * 4;
  int stride = gridDim.x * 256 * 4;
  for (int i = i0; i < n; i += stride) {
    float4 v = *reinterpret_cast<const float4*>(in + i);
    ushort4 o;
    o.x = f2bf(v.x); o.y = f2bf(v.y); o.z = f2bf(v.z); o.w = f2bf(v.w);
    *reinterpret_cast<ushort4*>(out + i) = o;
  }
}

// 4 weight matrices (1M elems each) in one dispatch; dsts contiguous slabs.
__global__ void cvt_weights(const float* __restrict__ s0, const float* __restrict__ s1,
                            const float* __restrict__ s2, const float* __restrict__ s3,
                            unsigned short* __restrict__ out) {
  const int NW = DDIM * DDIM;
  const float* src = (blockIdx.y == 0) ? s0 : (blockIdx.y == 1) ? s1
                    : (blockIdx.y == 2) ? s2 : s3;
  unsigned short* dst = out + (size_t)blockIdx.y * NW;
  int i0 = (blockIdx.x * 256 + threadIdx.x) * 4;
  int stride = gridDim.x * 256 * 4;
  for (int i = i0; i < NW; i += stride) {
    float4 v = *reinterpret_cast<const float4*>(src + i);
    ushort4 o;
    o.x = f2bf(v.x); o.y = f2bf(v.y); o.z = f2bf(v.z); o.w = f2bf(v.w);
    *reinterpret_cast<ushort4*>(dst + i) = o;
  }
}

// ================= 8-phase deep-pipelined GEMM: BM=128, BN=256, BK=64 ========
// NT-GEMM, K=1024 fixed. 512 threads = 8 waves (2M x 4N), wave output 64x64.
// LDS 96 KB: A-slabs 4 x 8KB (2 dbuf x 2 k-half, each [128r][32c] swizzled),
//            B-slabs 4 x 16KB (2 dbuf x 2 k-half, each [256r][32c] swizzled).
// Swizzle (per slab): unit u=row>>1 (128B), granule g=(row&1)*4+slot16,
//   physical p = g ^ (u&7); byte = u*128 + p*16.  (zero-conflict, verified R3)
// Pipeline: tile u phase k0 reads (buf u%2, slab k0); stages tile u+1's k1
//   slabs (freed 2 phases ago); phase k1 reads slab k1, stages tile u+2's k0
//   (freed at this phase start). vmcnt(6) per phase = 2 phases of loads in
//   flight; never drains to 0 in the loop.
// MODE 0: QKV  A=xb[8192,1024] B=Wqkv[3072,1024] C=bf16[8192,3072]+bias(sel)
// MODE 1: outp A=Ob[8192,1024] B=Wo[1024,1024]   C=f32[8192,1024]+bias
template<int MODE>
__global__ __launch_bounds__(512, 2)
void gemm8(const unsigned short* __restrict__ A,
           const unsigned short* __restrict__ B,
           const float* __restrict__ bias0,
           const float* __restrict__ bias1,
           const float* __restrict__ bias2,
           void* __restrict__ C)
{
  constexpr int NTI  = 64;
  constexpr int NTJ  = (MODE == 0) ? 12 : 4;
  constexpr int NT   = 16;       // K-tiles of 64 (K=1024)
  constexpr int LDAB = 1024;
  constexpr int CLD  = (MODE == 0) ? QKVN : DDIM;
  constexpr int BOFF = 16384;    // shorts: B slabs start (A = 4 x 4096)

  __shared__ unsigned short smem[49152];   // 96 KB

  const int nwg = NTI * NTJ;               // 768 or 256 (mult of 8)
  const int bid = blockIdx.x;
  const int swz = (bid & 7) * (nwg >> 3) + (bid >> 3);   // XCD-bijective
  const int ti  = swz % NTI;
  const int tj  = swz / NTI;

  const int tid  = threadIdx.x;
  const int wave = tid >> 6;
  const int lane = tid & 63;
  const int wm   = wave >> 2;    // 0..1
  const int wn   = wave & 3;     // 0..3

  const unsigned short* Ab = A + (size_t)ti * 128 * LDAB;
  const unsigned short* Bb = B + (size_t)tj * 256 * LDAB;

  // staging per-lane source coords (inverse swizzle; LDS dest stays linear)
  const int g0   = (lane & 7) ^ ((lane >> 3) & 7);
  const int rloc = 2 * (lane >> 3) + (g0 >> 2);   // row within 16-row wave slice
  const int colg = (g0 & 3) * 8;                  // elem offset within 32-col slab

  // fragment read coords (swizzled)
  const int s_ = lane >> 4, fr = lane & 15;
  const int pb = (((fr & 1) << 2) | s_) ^ (fr >> 1);
  const int eA = (wm * 32 + (fr >> 1)) * 64 + pb * 8;   // + m*512
  const int eB = (wn * 32 + (fr >> 1)) * 64 + pb * 8;   // + n*512

  f32x4 acc[4][4];
#pragma unroll
  for (int i = 0; i < 4; ++i)
#pragma unroll
    for (int j = 0; j < 4; ++j) acc[i][j] = (f32x4){0.f, 0.f, 0.f, 0.f};

#define STAGE_A(b, ks, kt_) \
  GLOAD16(Ab + (size_t)(16 * wave + rloc) * LDAB + (kt_) * 64 + (ks) * 32 + colg, \
          smem + ((b) * 2 + (ks)) * 4096 + wave * 512)

#define STAGE_B(b, ks, kt_) do {                                                          \
    const unsigned short* bsrc_ = Bb + (size_t)(16 * wave + rloc) * LDAB                  \
                                     + (kt_) * 64 + (ks) * 32 + colg;                     \
    unsigned short* bdst_ = smem + BOFF + ((b) * 2 + (ks)) * 8192 + wave * 512;           \
    GLOAD16(bsrc_, bdst_);                                                                \
    GLOAD16(bsrc_ + (size_t)128 * LDAB, bdst_ + 4096);                                    \
  } while (0)

#define PHASE(CB, KS, COND, SB, SKS, SKT) do {                                            \
    const unsigned short* As_ = smem + ((CB) * 2 + (KS)) * 4096;                          \
    const unsigned short* Bs_ = smem + BOFF + ((CB) * 2 + (KS)) * 8192;                   \
    bf16x8 af[4], bg[4];                                                                  \
    _Pragma("unroll")                                                                     \
    for (int m = 0; m < 4; ++m) af[m] = *(const bf16x8*)(As_ + eA + m * 512);             \
    _Pragma("unroll")                                                                     \
    for (int n = 0; n < 4; ++n) bg[n] = *(const bf16x8*)(Bs_ + eB + n * 512);             \
    if (COND) { STAGE_A(SB, SKS, SKT); STAGE_B(SB, SKS, SKT); }                           \
    asm volatile("s_waitcnt vmcnt(6)" ::: "memory");                                      \
    __builtin_amdgcn_s_barrier();                                                         \
    asm volatile("s_waitcnt lgkmcnt(0)" ::: "memory");                                    \
    __builtin_amdgcn_sched_barrier(0);                                                    \
    __builtin_amdgcn_s_setprio(1);                                                        \
    _Pragma("unroll")                                                                     \
    for (int m = 0; m < 4; ++m)                                                           \
      _Pragma("unroll")                                                                   \
      for (int n = 0; n < 4; ++n)                                                         \
        acc[m][n] = __builtin_amdgcn_mfma_f32_16x16x32_bf16(af[m], bg[n], acc[m][n], 0, 0, 0); \
    __builtin_amdgcn_s_setprio(0);                                                        \
    __builtin_amdgcn_s_barrier();                                                         \
  } while (0)

  // prologue: tile0 k0+k1, tile1 k0 (9 loads/wave); wait leaves newest 6
  STAGE_A(0, 0, 0); STAGE_B(0, 0, 0);
  STAGE_A(0, 1, 0); STAGE_B(0, 1, 0);
  STAGE_A(1, 0, 1); STAGE_B(1, 0, 1);
  asm volatile("s_waitcnt vmcnt(6)" ::: "memory");
  __builtin_amdgcn_s_barrier();

  for (int u = 0; u < NT; ++u) {
    const int cb = u & 1;
    PHASE(cb, 0, (u + 1 < NT), cb ^ 1, 1, u + 1);  // stage tile u+1's k1 slabs
    PHASE(cb, 1, (u + 2 < NT), cb,     0, u + 2);  // stage tile u+2's k0 slabs
  }
#undef PHASE
#undef STAGE_B
#undef STAGE_A

  // epilogue: C/D layout col = lane&15, row = (lane>>4)*4 + r
  const int row0 = ti * 128 + wm * 64;
  const int col0 = tj * 256 + wn * 64;
  const float* bp = bias0;
  if constexpr (MODE == 0) bp = (tj < 4) ? bias0 : ((tj < 8) ? bias1 : bias2);
#pragma unroll
  for (int m = 0; m < 4; ++m) {
#pragma unroll
    for (int n = 0; n < 4; ++n) {
#pragma unroll
      for (int r = 0; r < 4; ++r) {
        const int gr = row0 + m * 16 + (lane >> 4) * 4 + r;
        const int gc = col0 + n * 16 + (lane & 15);
        const float v = acc[m][n][r];
        if constexpr (MODE == 0) {
          ((unsigned short*)C)[(size_t)gr * CLD + gc] = f2bf(v + bp[gc & 1023]);
        } else {
          ((float*)C)[(size_t)gr * CLD + gc] = v + bp[gc];
        }
      }
    }
  }
}

// ============== 128x128 tri-buffered GEMM (R3, kept for scores/PV) ===========
// MODE 2: scores: per-batch triangular grid; A=Q sec, B=K sec of QKVb (ld 3072)
// MODE 3: PV: per-batch, A=P[b][2048,2048], B=Vt[b][1024,2048], K truncated
template<int MODE>
__global__ __launch_bounds__(256, 3)
void gemm_kernel(const unsigned short* __restrict__ A,
                 const unsigned short* __restrict__ B,
                 void* __restrict__ C)
{
  __shared__ unsigned short As[3][128 * 32];   // 3 x 8 KB
  __shared__ unsigned short Bs[3][128 * 32];   // 3 x 8 KB

  const int tid  = threadIdx.x;
  const int wave = tid >> 6;
  const int lane = tid & 63;
  const int wr   = wave >> 1;
  const int wc   = wave & 1;

  const unsigned short *Ab, *Bb;
  int lda, ldb, ktiles;
  int ti, tj, bz = 0;

  if constexpr (MODE == 2) {
    int t = blockIdx.x; bz = blockIdx.y;
    ti = 0;
    while ((ti + 1) * (ti + 2) / 2 <= t) ++ti;   // triangular decode
    tj = t - ti * (ti + 1) / 2;                  // tj <= ti
    Ab = A + (size_t)bz * SDIM * QKVN + (size_t)ti * 128 * QKVN;        lda = QKVN; // Q
    Bb = A + (size_t)bz * SDIM * QKVN + (size_t)tj * 128 * QKVN + 1024; ldb = QKVN; // K
    ktiles = DDIM / 32;
  } else { // MODE 3
    bz = blockIdx.y;
    ti = blockIdx.x >> 3;
    tj = blockIdx.x & 7;
    Ab = A + (size_t)bz * SDIM * SDIM + (size_t)ti * 128 * SDIM; lda = SDIM;
    Bb = B + (size_t)bz * DDIM * SDIM + (size_t)tj * 128 * SDIM; ldb = SDIM;
    ktiles = (ti + 1) * 4;
  }

  f32x4 acc[4][4];
#pragma unroll
  for (int i = 0; i < 4; ++i)
#pragma unroll
    for (int j = 0; j < 4; ++j) acc[i][j] = (f32x4){0.f, 0.f, 0.f, 0.f};

  const int g0   = (lane & 7) ^ (lane >> 3);
  const int rloc = 2 * (lane >> 3) + (g0 >> 2);
  const int colg = (g0 & 3) * 8;

  const int s_  = lane >> 4;
  const int fr  = lane & 15;
  const int p_  = (((fr & 1) << 2) | s_) ^ ((fr >> 1) & 7);
  const int fA  = wr * 2048 + (fr >> 1) * 64 + p_ * 8;
  const int fB  = wc * 2048 + (fr >> 1) * 64 + p_ * 8;

#define STAGE(buf, kt) do {                                                     \
    const size_t kb_ = (size_t)(kt) * 32 + colg;                                \
    GLOAD16(Ab + (size_t)(wave * 16 + rloc) * lda + kb_,      &As[buf][wave * 512]);       \
    GLOAD16(Ab + (size_t)(64 + wave * 16 + rloc) * lda + kb_, &As[buf][(wave + 4) * 512]); \
    GLOAD16(Bb + (size_t)(wave * 16 + rloc) * ldb + kb_,      &Bs[buf][wave * 512]);       \
    GLOAD16(Bb + (size_t)(64 + wave * 16 + rloc) * ldb + kb_, &Bs[buf][(wave + 4) * 512]); \
  } while (0)

  STAGE(0, 0);
  STAGE(1, 1);
  asm volatile("s_waitcnt vmcnt(4)" ::: "memory");
  __builtin_amdgcn_s_barrier();
  __builtin_amdgcn_sched_barrier(0);

  for (int kt = 0; kt < ktiles; ++kt) {
    const int cur = kt % 3;
    if (kt + 2 < ktiles) STAGE((kt + 2) % 3, kt + 2);

    bf16x8 af[4], bfv[4];
#pragma unroll
    for (int mi = 0; mi < 4; ++mi)
      af[mi] = *reinterpret_cast<const bf16x8*>(&As[cur][fA + mi * 512]);
#pragma unroll
    for (int ni = 0; ni < 4; ++ni)
      bfv[ni] = *reinterpret_cast<const bf16x8*>(&Bs[cur][fB + ni * 512]);

    __builtin_amdgcn_s_setprio(1);
#pragma unroll
    for (int mi = 0; mi < 4; ++mi)
#pragma unroll
      for (int ni = 0; ni < 4; ++ni)
        acc[mi][ni] = __builtin_amdgcn_mfma_f32_16x16x32_bf16(af[mi], bfv[ni], acc[mi][ni], 0, 0, 0);
    __builtin_amdgcn_s_setprio(0);

    asm volatile("s_waitcnt vmcnt(4)" ::: "memory");
    __builtin_amdgcn_s_barrier();
    __builtin_amdgcn_sched_barrier(0);
  }
#undef STAGE

  const int row0 = wr * 64, col0 = wc * 64;
#pragma unroll
  for (int mi = 0; mi < 4; ++mi) {
#pragma unroll
    for (int ni = 0; ni < 4; ++ni) {
#pragma unroll
      for (int r = 0; r < 4; ++r) {
        const int lr = row0 + mi * 16 + (lane >> 4) * 4 + r;
        const int lc = col0 + ni * 16 + (lane & 15);
        const float v = acc[mi][ni][r];
        if constexpr (MODE == 2) {
          const int gi = ti * 128 + lr, gj = tj * 128 + lc;
          float s = fabsf(v) * 0.03125f;            // |q.k| / sqrt(1024)
          if (gj > gi) s = -INFINITY;               // strictly-above diag
          ((unsigned short*)C)[(size_t)bz * SDIM * SDIM + (size_t)gi * SDIM + gj] = f2bf(s);
        } else {
          const int gi = ti * 128 + lr, gd = tj * 128 + lc;
          ((unsigned short*)C)[(size_t)bz * SDIM * DDIM + (size_t)gi * DDIM + gd] = f2bf(v);
        }
      }
    }
  }
}

// ---------------- one-pass vectorized row softmax ----------------
__global__ void softmax_rows(unsigned short* __restrict__ Sc) {
  const int rid = blockIdx.x;
  const int b = rid >> 11, i = rid & (SDIM - 1);
  unsigned short* row = Sc + ((size_t)b * SDIM + i) * SDIM;
  const int Lpad = ((i >> 7) + 1) << 7;  // next 128 boundary (PV is 128-tiled)
  const int tid  = threadIdx.x;
  const bool act = tid * 8 < Lpad;

  float v[8];
  float m = 0.0f;
  if (act) {
    u16x8 u = *reinterpret_cast<const u16x8*>(row + tid * 8);
#pragma unroll
    for (int e = 0; e < 8; ++e) { v[e] = bf2f(u[e]); m = fmaxf(m, v[e]); }
  }
#pragma unroll
  for (int off = 32; off; off >>= 1) m = fmaxf(m, __shfl_down(m, off));
  __shared__ float redm[4], reds[4];
  if ((tid & 63) == 0) redm[tid >> 6] = m;
  __syncthreads();
  const float M = fmaxf(fmaxf(redm[0], redm[1]), fmaxf(redm[2], redm[3]));

  float s = 0.0f;
  if (act) {
#pragma unroll
    for (int e = 0; e < 8; ++e) { v[e] = expf(v[e] - M); s += v[e]; }
  }
#pragma unroll
  for (int off = 32; off; off >>= 1) s += __shfl_down(s, off);
  if ((tid & 63) == 0) reds[tid >> 6] = s;
  __syncthreads();
  const float inv = 1.0f / (reds[0] + reds[1] + reds[2] + reds[3]);

  if (act) {
    ushort4 o0, o1;
    o0.x = f2bf(v[0] * inv); o0.y = f2bf(v[1] * inv);
    o0.z = f2bf(v[2] * inv); o0.w = f2bf(v[3] * inv);
    o1.x = f2bf(v[4] * inv); o1.y = f2bf(v[5] * inv);
    o1.z = f2bf(v[6] * inv); o1.w = f2bf(v[7] * inv);
    *reinterpret_cast<ushort4*>(row + tid * 8)     = o0;
    *reinterpret_cast<ushort4*>(row + tid * 8 + 4) = o1;
  }
}

// ---------------- bf16 transpose: V section of QKVb -> Vt[B,1024,2048] -------
__global__ void transpose_v(const unsigned short* __restrict__ qkv,
                            unsigned short* __restrict__ out) {
  __shared__ unsigned short tile[64][65];
  const int b = blockIdx.z;
  const unsigned short* in = qkv + (size_t)b * SDIM * QKVN + 2048;  // V section
  unsigned short* o = out + (size_t)b * DDIM * SDIM;
  const int tx = threadIdx.x & 63;
  const int ty = threadIdx.x >> 6;
  const int r0 = blockIdx.y * 64;
  const int c0 = blockIdx.x * 64;
  for (int r = ty; r < 64; r += 4)
    tile[r][tx] = in[(size_t)(r0 + r) * QKVN + c0 + tx];
  __syncthreads();
  for (int r = ty; r < 64; r += 4)
    o[(size_t)(c0 + r) * SDIM + r0 + tx] = tile[tx][r];
}

// ---------------- host launch ----------------
extern "C" void kernel_launch(void* const* d_in, const int* in_sizes, int n_in,
                              void* d_out, int out_size, void* d_ws, size_t ws_size,
                              hipStream_t stream) {
  const float* x  = (const float*)d_in[0];
  const float* Wq = (const float*)d_in[1];
  const float* bq = (const float*)d_in[2];
  const float* Wk = (const float*)d_in[3];
  const float* bk = (const float*)d_in[4];
  const float* Wv = (const float*)d_in[5];
  const float* bv = (const float*)d_in[6];
  const float* Wo = (const float*)d_in[7];
  const float* bo = (const float*)d_in[8];
  float* out = (float*)d_out;

  const size_t NTOK = (size_t)BATCH * SDIM;       // 8192
  unsigned short* ws = (unsigned short*)d_ws;
  unsigned short* xb   = ws;                          // [8192,1024]
  unsigned short* wqkv = xb + NTOK * DDIM;            // [3072,1024]
  unsigned short* wo   = wqkv + (size_t)QKVN * DDIM;  // [1024,1024]
  unsigned short* QKVb = wo + (size_t)DDIM * DDIM;    // [8192,3072]
  unsigned short* Vt   = QKVb + NTOK * QKVN;          // [B,1024,2048]
  unsigned short* Ob   = Vt + NTOK * DDIM;            // [8192,1024]
  unsigned short* Sc   = Ob + NTOK * DDIM;            // [B,2048,2048]

  const int NX = (int)(NTOK * DDIM);              // 8M

  cvt_f32_bf16<<<2048, 256, 0, stream>>>(x, xb, NX);
  cvt_weights<<<dim3(256, 4), 256, 0, stream>>>(Wq, Wk, Wv, Wo, wqkv);

  // fused QKV projection -> QKVb [8192, 3072]   (768 blocks = 3/CU exact)
  gemm8<0><<<768, 512, 0, stream>>>(xb, wqkv, bq, bk, bv, QKVb);

  // scores (lower-triangular tiles): Sc = bf16(|Q@K^T|/32), -inf above diag
  gemm_kernel<2><<<dim3(136, BATCH), 256, 0, stream>>>(QKVb, nullptr, Sc);

  // one-pass softmax (in place; padding becomes exact 0)
  softmax_rows<<<BATCH * SDIM, 256, 0, stream>>>(Sc);

  // V transpose for NT PV gemm
  transpose_v<<<dim3(DDIM / 64, SDIM / 64, BATCH), 256, 0, stream>>>(QKVb, Vt);

  // O = P @ V (causal-truncated K)
  gemm_kernel<3><<<dim3(128, BATCH), 256, 0, stream>>>(Sc, Vt, Ob);

  // final projection -> fp32 out   (256 blocks = 1/CU exact)
  gemm8<1><<<256, 512, 0, stream>>>(Ob, wo, bo, nullptr, nullptr, out);
}